// Round 5
// baseline (22.518 us; speedup 1.0000x reference)
//
#include <hip/hip_runtime.h>

// YOLO layer: (64, 30, 76, 76) f32 -> (64, 3*76*76, 10) f32
// out[b, a*G*G + gy*G + gx, :] =
//   [ (sig(x0)+gx)*8, (sig(x1)+gy)*8, exp(x2)*aw, exp(x3)*ah,
//     x4, x5, sig(x6), sig(x7), sig(x8), sig(x9) ]
// where xc = x[b, a*10 + c, gy, gx], aw = anchors[a,0], ah = anchors[a,1].

#define NB 64
#define NA 3
#define NC 3
#define GG 76
#define PLANE (GG * GG)          // 5776
#define CH (NC + 7)              // 10
#define STRIDE_F 8.0f            // 608 / 76

__device__ __forceinline__ float sigf(float v) {
    return 1.0f / (1.0f + expf(-v));
}

__global__ __launch_bounds__(256) void yolo_kernel(const float* __restrict__ x,
                                                   const float* __restrict__ anchors,
                                                   float* __restrict__ out,
                                                   int total) {
    int idx = blockIdx.x * blockDim.x + threadIdx.x;
    if (idx >= total) return;

    // idx = (b*NA + a)*PLANE + s, s = gy*GG + gx
    int s  = idx % PLANE;
    int ba = idx / PLANE;
    int a  = ba % NA;
    int gy = s / GG;
    int gx = s - gy * GG;

    const float* xin = x + (size_t)ba * (CH * PLANE) + s;

    float v[CH];
#pragma unroll
    for (int c = 0; c < CH; ++c) v[c] = xin[(size_t)c * PLANE];

    float aw = anchors[a * 4 + 0];
    float ah = anchors[a * 4 + 1];

    float o[CH];
    o[0] = (sigf(v[0]) + (float)gx) * STRIDE_F;
    o[1] = (sigf(v[1]) + (float)gy) * STRIDE_F;
    o[2] = expf(v[2]) * aw;
    o[3] = expf(v[3]) * ah;
    o[4] = v[4];
    o[5] = v[5];
    o[6] = sigf(v[6]);
    o[7] = sigf(v[7]);
    o[8] = sigf(v[8]);
    o[9] = sigf(v[9]);

    // output base = idx*10 floats = idx*40 bytes -> 8-byte aligned, use float2
    float* op = out + (size_t)idx * CH;
    float2* op2 = reinterpret_cast<float2*>(op);
#pragma unroll
    for (int k = 0; k < CH / 2; ++k) {
        op2[k] = make_float2(o[2 * k], o[2 * k + 1]);
    }
}

extern "C" void kernel_launch(void* const* d_in, const int* in_sizes, int n_in,
                              void* d_out, int out_size, void* d_ws, size_t ws_size,
                              hipStream_t stream) {
    const float* x       = (const float*)d_in[0];
    const float* anchors = (const float*)d_in[1];
    float* out           = (float*)d_out;

    int total = NB * NA * PLANE;  // 1,108,992 threads
    int block = 256;
    int grid  = (total + block - 1) / block;
    yolo_kernel<<<grid, block, 0, stream>>>(x, anchors, out, total);
}

// Round 6
// 19.305 us; speedup vs baseline: 1.1664x; 1.1664x over previous
//
#include <hip/hip_runtime.h>

// YOLO layer: (64, 30, 76, 76) f32 -> (64, 3*76*76, 10) f32
// out[b, a*G*G + gy*G + gx, :] =
//   [ (sig(x0)+gx)*8, (sig(x1)+gy)*8, exp(x2)*aw, exp(x3)*ah,
//     x4, x5, sig(x6), sig(x7), sig(x8), sig(x9) ]
// Each thread: 4 consecutive grid cells (float4 loads from each of 10 planes),
// stage 4x10 outputs in LDS (output-linear), block writes 40 KiB contiguously
// as fully-coalesced float4 stores.

#define NB 64
#define NA 3
#define GG 76
#define PLANE (GG * GG)                    // 5776
#define CH 10
#define BLK 256
#define QPT 4                              // grid cells per thread
#define QUADS_PER_BA (PLANE / QPT)         // 1444
#define TOTAL_QUADS (NB * NA * QUADS_PER_BA) // 277248
#define GRID_BLKS (TOTAL_QUADS / BLK)      // 1083 exactly, no tail
#define F4_PER_BLK (BLK * QPT * CH / 4)    // 2560 float4 = 40 KiB
#define PLANE_F4 (PLANE / 4)               // 1444
#define STRIDE_F 8.0f                      // 608 / 76

__device__ __forceinline__ float sigf(float v) {
    return 1.0f / (1.0f + __expf(-v));
}

__global__ __launch_bounds__(BLK) void yolo_kernel(const float* __restrict__ x,
                                                   const float* __restrict__ anchors,
                                                   float* __restrict__ out) {
    __shared__ float4 lds4[F4_PER_BLK];    // 40960 B, output-linear for this block

    const int t  = threadIdx.x;
    const int q  = blockIdx.x * BLK + t;   // global quad index
    const int ba = q / QUADS_PER_BA;       // batch*anchor plane group
    const int qs = q - ba * QUADS_PER_BA;
    const int s  = qs * QPT;               // spatial index, multiple of 4
    const int gy = s / GG;
    const int gx = s - gy * GG;            // multiple of 4; gx..gx+3 same row
    const int a  = ba % NA;

    const float4* __restrict__ xin =
        reinterpret_cast<const float4*>(x + (size_t)ba * (CH * PLANE) + s);
    const float aw = anchors[a * 4 + 0];
    const float ah = anchors[a * 4 + 1];

    // o[10*l + c] = output channel c of local cell l. Static indices only.
    float4 oq[CH];
    float* o = reinterpret_cast<float*>(oq);

    float4 v;
    v = xin[0 * PLANE_F4];
    o[ 0] = (sigf(v.x) + (float)(gx + 0)) * STRIDE_F;
    o[10] = (sigf(v.y) + (float)(gx + 1)) * STRIDE_F;
    o[20] = (sigf(v.z) + (float)(gx + 2)) * STRIDE_F;
    o[30] = (sigf(v.w) + (float)(gx + 3)) * STRIDE_F;

    v = xin[1 * PLANE_F4];
    const float fgy = (float)gy;
    o[ 1] = (sigf(v.x) + fgy) * STRIDE_F;
    o[11] = (sigf(v.y) + fgy) * STRIDE_F;
    o[21] = (sigf(v.z) + fgy) * STRIDE_F;
    o[31] = (sigf(v.w) + fgy) * STRIDE_F;

    v = xin[2 * PLANE_F4];
    o[ 2] = __expf(v.x) * aw;  o[12] = __expf(v.y) * aw;
    o[22] = __expf(v.z) * aw;  o[32] = __expf(v.w) * aw;

    v = xin[3 * PLANE_F4];
    o[ 3] = __expf(v.x) * ah;  o[13] = __expf(v.y) * ah;
    o[23] = __expf(v.z) * ah;  o[33] = __expf(v.w) * ah;

    v = xin[4 * PLANE_F4];
    o[ 4] = v.x; o[14] = v.y; o[24] = v.z; o[34] = v.w;

    v = xin[5 * PLANE_F4];
    o[ 5] = v.x; o[15] = v.y; o[25] = v.z; o[35] = v.w;

    v = xin[6 * PLANE_F4];
    o[ 6] = sigf(v.x); o[16] = sigf(v.y); o[26] = sigf(v.z); o[36] = sigf(v.w);

    v = xin[7 * PLANE_F4];
    o[ 7] = sigf(v.x); o[17] = sigf(v.y); o[27] = sigf(v.z); o[37] = sigf(v.w);

    v = xin[8 * PLANE_F4];
    o[ 8] = sigf(v.x); o[18] = sigf(v.y); o[28] = sigf(v.z); o[38] = sigf(v.w);

    v = xin[9 * PLANE_F4];
    o[ 9] = sigf(v.x); o[19] = sigf(v.y); o[29] = sigf(v.z); o[39] = sigf(v.w);

    // Stage: thread t's 40 floats are output dwords [40t, 40t+40) of this
    // block's region -> LDS is exactly output-linear.
#pragma unroll
    for (int k = 0; k < CH; ++k) lds4[t * CH + k] = oq[k];

    __syncthreads();

    // Fully-coalesced block store: 2560 float4, 10 per thread, lanes contiguous.
    float4* __restrict__ out4 =
        reinterpret_cast<float4*>(out) + (size_t)blockIdx.x * F4_PER_BLK;
#pragma unroll
    for (int j = 0; j < CH; ++j) out4[t + BLK * j] = lds4[t + BLK * j];
}

extern "C" void kernel_launch(void* const* d_in, const int* in_sizes, int n_in,
                              void* d_out, int out_size, void* d_ws, size_t ws_size,
                              hipStream_t stream) {
    const float* x       = (const float*)d_in[0];
    const float* anchors = (const float*)d_in[1];
    float* out           = (float*)d_out;

    yolo_kernel<<<GRID_BLKS, BLK, 0, stream>>>(x, anchors, out);
}

// Round 7
// 18.855 us; speedup vs baseline: 1.1943x; 1.0239x over previous
//
#include <hip/hip_runtime.h>

// YOLO layer: (64, 30, 76, 76) f32 -> (64, 3*76*76, 10) f32
// out[b, a*G*G + gy*G + gx, :] =
//   [ (sig(x0)+gx)*8, (sig(x1)+gy)*8, exp(x2)*aw, exp(x3)*ah,
//     x4, x5, sig(x6), sig(x7), sig(x8), sig(x9) ]
// R7: QPT=2 (float2 loads), 20 KiB LDS/block -> 8 blocks/CU (32 waves/CU),
// channel-pair interleaved LDS staging (float2, <=2-way bank alias = free),
// fully-coalesced float4 readback + global store. Grid 2166 blocks, no tail.

#define NB 64
#define NA 3
#define GG 76
#define PLANE (GG * GG)                      // 5776
#define CH 10
#define BLK 256
#define QPT 2
#define PAIRS_PER_BA (PLANE / QPT)           // 2888
#define TOTAL_PAIRS (NB * NA * PAIRS_PER_BA) // 554496
#define GRID_BLKS (TOTAL_PAIRS / BLK)        // 2166 exactly
#define F2_PER_BLK (BLK * CH)                // 2560 float2 = 20 KiB
#define F4_PER_BLK (F2_PER_BLK / 2)          // 1280 float4
#define STRIDE_F 8.0f                        // 608 / 76

__device__ __forceinline__ float sigf(float v) {
    return 1.0f / (1.0f + __expf(-v));
}

__global__ __launch_bounds__(BLK, 8) void yolo_kernel(const float* __restrict__ x,
                                                      const float* __restrict__ anchors,
                                                      float* __restrict__ out) {
    __shared__ float2 lds2[F2_PER_BLK];      // output-linear for this block

    const int t  = threadIdx.x;
    const int q  = blockIdx.x * BLK + t;     // global cell-pair index
    const int ba = q / PAIRS_PER_BA;
    const int ps = q - ba * PAIRS_PER_BA;
    const int s  = ps * QPT;                 // even; gx even, no row wrap
    const int gy = s / GG;
    const int gx = s - gy * GG;
    const int a  = ba % NA;

    const float2* __restrict__ xin =
        reinterpret_cast<const float2*>(x + (size_t)ba * (CH * PLANE)) + ps;
    const float aw = anchors[a * 4 + 0];
    const float ah = anchors[a * 4 + 1];
    const float fgy = (float)gy;

    // Thread t owns output dwords [20t, 20t+20): cell0 ch0-9, cell1 ch0-9.
    // lds2 index base = 10t; cell0 pair k at base+k, cell1 pair k at base+5+k.
    const int base = CH * t;

    float2 v0 = xin[0 * (PLANE / 2)];
    float2 v1 = xin[1 * (PLANE / 2)];
    lds2[base + 0] = make_float2((sigf(v0.x) + (float)gx) * STRIDE_F,
                                 (sigf(v1.x) + fgy) * STRIDE_F);
    lds2[base + 5] = make_float2((sigf(v0.y) + (float)(gx + 1)) * STRIDE_F,
                                 (sigf(v1.y) + fgy) * STRIDE_F);

    float2 v2 = xin[2 * (PLANE / 2)];
    float2 v3 = xin[3 * (PLANE / 2)];
    lds2[base + 1] = make_float2(__expf(v2.x) * aw, __expf(v3.x) * ah);
    lds2[base + 6] = make_float2(__expf(v2.y) * aw, __expf(v3.y) * ah);

    float2 v4 = xin[4 * (PLANE / 2)];
    float2 v5 = xin[5 * (PLANE / 2)];
    lds2[base + 2] = make_float2(v4.x, v5.x);
    lds2[base + 7] = make_float2(v4.y, v5.y);

    float2 v6 = xin[6 * (PLANE / 2)];
    float2 v7 = xin[7 * (PLANE / 2)];
    lds2[base + 3] = make_float2(sigf(v6.x), sigf(v7.x));
    lds2[base + 8] = make_float2(sigf(v6.y), sigf(v7.y));

    float2 v8 = xin[8 * (PLANE / 2)];
    float2 v9 = xin[9 * (PLANE / 2)];
    lds2[base + 4] = make_float2(sigf(v8.x), sigf(v9.x));
    lds2[base + 9] = make_float2(sigf(v8.y), sigf(v9.y));

    __syncthreads();

    // Block's output region is contiguous: 1280 float4, 5 per thread.
    const float4* __restrict__ lds4 = reinterpret_cast<const float4*>(lds2);
    float4* __restrict__ out4 =
        reinterpret_cast<float4*>(out) + (size_t)blockIdx.x * F4_PER_BLK;
#pragma unroll
    for (int j = 0; j < 5; ++j) out4[BLK * j + t] = lds4[BLK * j + t];
}

extern "C" void kernel_launch(void* const* d_in, const int* in_sizes, int n_in,
                              void* d_out, int out_size, void* d_ws, size_t ws_size,
                              hipStream_t stream) {
    const float* x       = (const float*)d_in[0];
    const float* anchors = (const float*)d_in[1];
    float* out           = (float*)d_out;

    yolo_kernel<<<GRID_BLKS, BLK, 0, stream>>>(x, anchors, out);
}